// Round 18
// baseline (35.688 us; speedup 1.0000x reference)
//
#include <hip/hip_runtime.h>
#include <hip/hip_bf16.h>

// GNN layer: out = (A @ x) @ W^T + bias,  A = fixed 8-neighbor stencil.
// x[64][65536] f32, W[256][65536] f32, bias[256], out[64][256] f32.
// R18: fused kernel with 2D spatial tiling (x traffic 96->21 MB), NO inline
// asm anywhere (R14/R15 failures tracked to asm-pinned register pressure).
// Block tid -> 16x16 spatial tile; x halo staged bf16 in LDS with FLAT
// addressing (reproduces reference flat-wrap semantics exactly); stencil
// from LDS -> hs; R10-proven MFMA phase with strided W addressing.

#define MB    64
#define NOUT  256
#define KDIM  65536
#define NTOT  (MB * KDIM)
#define OTOT  (MB * NOUT)       // 16384
#define LSTR  272               // hs row stride (ushorts)
#define XSM   432               // xs ushorts per m: 18 rows * 24 cols
#define XSR   24                // xs cols per staged row

typedef __attribute__((ext_vector_type(8))) short bf16x8;
typedef __attribute__((ext_vector_type(8))) unsigned short ushort8v;
typedef __attribute__((ext_vector_type(4))) float f32x4;

__device__ __forceinline__ ushort f2bf(float f) {
    __hip_bfloat16 h = __float2bfloat16(f);
    return *reinterpret_cast<ushort*>(&h);
}
__device__ __forceinline__ float bf2f(ushort u) {
    return __uint_as_float((unsigned)u << 16);
}

// ---------------------------------------------------------------------------
// FUSED kernel. 256 blocks x 1024 threads. Block tid -> tile rows
// r0..r0+15, cols c0..c0+15; k_local = rs*16+cs <-> global k =
// (r0+rs)*256 + (c0+cs).
//   A1: stage x -> xs bf16 [64 m][18 rows][24 cols]; staged chunk addresses
//       are FLAT (row*256 + col, col in [c0-4, c0+19]), so edge halo slots
//       hold the flat-previous/next elements, matching reference semantics.
//       Clamped (<0, >NTOT-4) and cross-batch slots only feed weight-0 terms.
//   A2: stencil from xs -> hs[m][k_local].
//   B : 8 MFMA k-steps x 4 m-tiles (R10 codegen); W strided per k_local map:
//       global k addr = row_n*KDIM + (r0+(lg>>1))*256 + c0 + (lg&1)*8 + ks*512.
// part[tid][n][m] bf16. XCD swizzle: tid = (b%8)*32 + b/8.
// ---------------------------------------------------------------------------
__global__ __launch_bounds__(1024, 4) void fused_sg(const float* __restrict__ x,
                                                    const float* __restrict__ W,
                                                    ushort* __restrict__ part) {
    __shared__ ushort xs[MB * XSM];      // 55296 B
    __shared__ ushort hs[MB * LSTR];     // 34816 B
    const int b   = blockIdx.x;
    const int tid = (b & 7) * 32 + (b >> 3);     // 0..255
    const int r0  = (tid >> 4) << 4;
    const int c0  = (tid & 15) << 4;
    const int t   = threadIdx.x;

    // ---- A1: stage x -> xs (6912 float4 chunks) ----
    #pragma unroll
    for (int it = 0; it < 7; ++it) {
        const int cid = t + it * 1024;
        if (cid < 6912) {
            const int m   = cid / 108;           // 108 = 18 rows * 6 chunks
            const int rem = cid - m * 108;
            const int rr  = rem / 6;
            const int q   = rem - rr * 6;
            int a = m * KDIM + (r0 + rr - 1) * 256 + (c0 - 4 + q * 4);
            a = a < 0 ? 0 : (a > NTOT - 4 ? NTOT - 4 : a);
            const float4 v = *(const float4*)(x + a);
            ushort4 s;
            s.x = f2bf(v.x); s.y = f2bf(v.y); s.z = f2bf(v.z); s.w = f2bf(v.w);
            *(ushort4*)&xs[m * XSM + rr * XSR + q * 4] = s;
        }
    }
    __syncthreads();

    // ---- A2: stencil from xs -> hs ----
    {
        const int m2 = t >> 4;                   // 0..63
        const int rs = t & 15;                   // tile row of the 16 outputs
        ushort8v rowv[3][3];
        #pragma unroll
        for (int r = 0; r < 3; ++r) {
            const int base = m2 * XSM + (rs + r) * XSR;
            rowv[r][0] = *(const ushort8v*)&xs[base];
            rowv[r][1] = *(const ushort8v*)&xs[base + 8];
            rowv[r][2] = *(const ushort8v*)&xs[base + 16];
        }
#define XE(R, C) bf2f((ushort)rowv[R][(C) >> 3][(C) & 7])
        const int ibase = (r0 + rs) * 256 + c0;  // flat idx of cs=0 output
        ushort8v h0, h1v;
        if (ibase >= 514 && ibase <= 65006) {    // [i-257, i+257] all centers
            #pragma unroll
            for (int cs = 0; cs < 16; ++cs) {
                const float nb = XE(1, cs + 3) + XE(1, cs + 5)
                               + XE(0, cs + 3) + XE(0, cs + 4) + XE(0, cs + 5)
                               + XE(2, cs + 3) + XE(2, cs + 4) + XE(2, cs + 5);
                const ushort o = f2bf(fmaf(2.0f, nb, XE(1, cs + 4)));
                if (cs < 8) h0[cs] = o; else h1v[cs - 8] = o;
            }
        } else {
            #pragma unroll
            for (int cs = 0; cs < 16; ++cs) {
                const int i = ibase + cs;
                const float ci = ((unsigned)(i - 257) <= (65278u - 257u)) ? 1.0f : 0.0f;
                float s = XE(1, cs + 4);
                // flat offsets {-1,+1,-257,-256,-255,+255,+256,+257} map to
                // (row, col) slots via flat staging:
                float v0 = XE(1, cs + 3), v1 = XE(1, cs + 5);
                float v2 = XE(0, cs + 3), v3 = XE(0, cs + 4), v4 = XE(0, cs + 5);
                float v5 = XE(2, cs + 3), v6 = XE(2, cs + 4), v7 = XE(2, cs + 5);
                const int joff[8] = {-1, 1, -257, -256, -255, 255, 256, 257};
                const float vals[8] = {v0, v1, v2, v3, v4, v5, v6, v7};
                #pragma unroll
                for (int e = 0; e < 8; ++e) {
                    const int jf = i + joff[e];
                    const float cj = ((unsigned)(jf - 257) <= (65278u - 257u)) ? 1.0f : 0.0f;
                    s = fmaf(ci + cj, vals[e], s);
                }
                const ushort o = f2bf(s);
                if (cs < 8) h0[cs] = o; else h1v[cs - 8] = o;
            }
        }
#undef XE
        *(ushort8v*)&hs[m2 * LSTR + rs * 16]     = h0;
        *(ushort8v*)&hs[m2 * LSTR + rs * 16 + 8] = h1v;
    }
    __syncthreads();

    // ---- B: MFMA over 8 k-steps x 4 m-tiles (R10 codegen, strided W) ----
    const int nt = t >> 6;                       // 0..15 n-tile
    const int l  = t & 63;
    const int lr = l & 15;
    const int lg = l >> 4;

    f32x4 acc0 = (f32x4){0.f,0.f,0.f,0.f}, acc1 = (f32x4){0.f,0.f,0.f,0.f};
    f32x4 acc2 = (f32x4){0.f,0.f,0.f,0.f}, acc3 = (f32x4){0.f,0.f,0.f,0.f};

    // lane's k_local per step ks: ks*32 + lg*8 + e  ->  global flat W col
    // (r0 + 2ks + (lg>>1))*256 + c0 + (lg&1)*8 + e
    const float* wb = W + (size_t)(nt * 16 + lr) * KDIM
                        + (size_t)(r0 + (lg >> 1)) * 256 + c0 + (lg & 1) * 8;

    #pragma unroll
    for (int ks = 0; ks < 8; ++ks) {
        float4 w0 = *(const float4*)(wb + ks * 512);
        float4 w1 = *(const float4*)(wb + ks * 512 + 4);
        union { ushort u[8]; bf16x8 v; } bb;
        bb.u[0] = f2bf(w0.x); bb.u[1] = f2bf(w0.y);
        bb.u[2] = f2bf(w0.z); bb.u[3] = f2bf(w0.w);
        bb.u[4] = f2bf(w1.x); bb.u[5] = f2bf(w1.y);
        bb.u[6] = f2bf(w1.z); bb.u[7] = f2bf(w1.w);
        bf16x8 af0 = *(const bf16x8*)&hs[(0 * 16 + lr) * LSTR + lg * 8 + ks * 32];
        bf16x8 af1 = *(const bf16x8*)&hs[(1 * 16 + lr) * LSTR + lg * 8 + ks * 32];
        bf16x8 af2 = *(const bf16x8*)&hs[(2 * 16 + lr) * LSTR + lg * 8 + ks * 32];
        bf16x8 af3 = *(const bf16x8*)&hs[(3 * 16 + lr) * LSTR + lg * 8 + ks * 32];
        acc0 = __builtin_amdgcn_mfma_f32_16x16x32_bf16(af0, bb.v, acc0, 0, 0, 0);
        acc1 = __builtin_amdgcn_mfma_f32_16x16x32_bf16(af1, bb.v, acc1, 0, 0, 0);
        acc2 = __builtin_amdgcn_mfma_f32_16x16x32_bf16(af2, bb.v, acc2, 0, 0, 0);
        acc3 = __builtin_amdgcn_mfma_f32_16x16x32_bf16(af3, bb.v, acc3, 0, 0, 0);
    }

    // D layout: n-col = lane&15, m = (lane>>4)*4 + reg (m89/m91-verified).
    ushort* pb = part + (size_t)tid * OTOT + (size_t)(nt * 16 + lr) * MB;
    ushort4 s;
    s.x = f2bf(acc0[0]); s.y = f2bf(acc0[1]); s.z = f2bf(acc0[2]); s.w = f2bf(acc0[3]);
    *(ushort4*)(pb + 0 * 16 + lg * 4) = s;
    s.x = f2bf(acc1[0]); s.y = f2bf(acc1[1]); s.z = f2bf(acc1[2]); s.w = f2bf(acc1[3]);
    *(ushort4*)(pb + 1 * 16 + lg * 4) = s;
    s.x = f2bf(acc2[0]); s.y = f2bf(acc2[1]); s.z = f2bf(acc2[2]); s.w = f2bf(acc2[3]);
    *(ushort4*)(pb + 2 * 16 + lg * 4) = s;
    s.x = f2bf(acc3[0]); s.y = f2bf(acc3[1]); s.z = f2bf(acc3[2]); s.w = f2bf(acc3[3]);
    *(ushort4*)(pb + 3 * 16 + lg * 4) = s;
}

// ---------------------------------------------------------------------------
// Reduce 256 bf16 partials (+bias) -> f32 out[64][256].
// 1024 blocks x 256 thr: 16 threads/output, 16 chunks each, LDS combine.
// part[kc][n*64+m]; out[m][n]. (R17-proven)
// ---------------------------------------------------------------------------
__global__ __launch_bounds__(256) void reduce_bf16(const ushort* __restrict__ part,
                                                   const float* __restrict__ bias,
                                                   float* __restrict__ out) {
    __shared__ float red[256];
    const int ol = threadIdx.x & 15;
    const int cg = threadIdx.x >> 4;             // 0..15 -> 16 chunks each
    const int o  = blockIdx.x * 16 + ol;         // 0..16383
    const ushort* p = part + (size_t)cg * 16 * OTOT + o;
    float s0 = 0.f, s1 = 0.f, s2 = 0.f, s3 = 0.f;
    #pragma unroll
    for (int i = 0; i < 16; i += 4) {
        s0 += bf2f(p[(size_t)(i + 0) * OTOT]);
        s1 += bf2f(p[(size_t)(i + 1) * OTOT]);
        s2 += bf2f(p[(size_t)(i + 2) * OTOT]);
        s3 += bf2f(p[(size_t)(i + 3) * OTOT]);
    }
    red[threadIdx.x] = (s0 + s1) + (s2 + s3);
    __syncthreads();
    if (cg == 0) {
        float v = red[ol];
        #pragma unroll
        for (int jj = 1; jj < 16; ++jj) v += red[jj * 16 + ol];
        const int n = o >> 6, m = o & 63;
        out[m * NOUT + n] = v + bias[n];
    }
}

// ---------------------------------------------------------------------------
extern "C" void kernel_launch(void* const* d_in, const int* in_sizes, int n_in,
                              void* d_out, int out_size, void* d_ws, size_t ws_size,
                              hipStream_t stream) {
    const float* x    = (const float*)d_in[0];
    const float* W    = (const float*)d_in[1];
    const float* bias = (const float*)d_in[2];
    float* out = (float*)d_out;

    ushort* part = (ushort*)d_ws;                // 256*16384*2 = 8 MiB

    fused_sg<<<256, 1024, 0, stream>>>(x, W, part);
    reduce_bf16<<<OTOT / 16, 256, 0, stream>>>(part, bias, out);
}